// Round 3
// baseline (21823.122 us; speedup 1.0000x reference)
//
#include <hip/hip_runtime.h>
#include <stdint.h>

// ---------------------------------------------------------------------------
// 2-layer LSTM (T=512, B=256, IN=64, H=1024) + Linear(H->1) + sigmoid.
// One persistent kernel, 256 blocks (1/CU), layers software-pipelined
// (phase p = layer1(p) + layer2(p-1)), ONE group barrier per phase.
// NEW vs round 1:
//  * K-split waves: each of 4 waves computes the FULL 64x64 output tile over
//    a K/4 slice -> weights+activations read ONCE per block (803 KB/CU/phase
//    instead of 2.0 MB). Cross-wave reduce via 64 KB LDS, XOR-swizzled
//    (col ^= kq<<4) so write/read are <=2-way bank conflicts (free).
//  * Barrier is per-m-group (64 blocks): all cross-block traffic (H1/H2 rows)
//    stays within the m-group. 8 leaves keyed by bid&7 (deterministic) + root.
// ---------------------------------------------------------------------------

#define TT   512
#define BAT  256
#define INP  64
#define HID  1024
#define KA   1088   // INP + HID   (concat [x_t | h1])
#define KB   2048   // HID + HID   (concat [h1 | h2])
#define SZH  (BAT*HID)
#define NBLK 256
#define NTHR 256

typedef __attribute__((ext_vector_type(8))) short bf16x8;
typedef __attribute__((ext_vector_type(4))) float f32x4;

// workspace byte offsets (all 256-aligned)
#define OFF_BA   0ull          // bf16 [4096][1088] packed W layer1
#define OFF_BB   8912896ull    // bf16 [4096][2048] packed W layer2
#define OFF_XB   25690112ull   // bf16 x [512][256][64]
#define OFF_H1   42467328ull   // bf16 h1 [2][256][1024] (double buffer)
#define OFF_H2   43515904ull   // bf16 h2 [2][256][1024]
#define OFF_C1   44564480ull   // f32 c1 [256][1024]
#define OFF_C2   45613056ull   // f32 c2 [256][1024]
#define OFF_Y    46661632ull   // f32 yacc [512][256]
#define OFF_B1P  47185920ull   // f32 packed bias layer1 [4096]
#define OFF_B2P  47202304ull   // f32 packed bias layer2 [4096]
#define OFF_BAR  47218688ull   // u32 barriers: 4 groups x (8 leaves + root) x 32 u32
#define WS_END   47226880ull   // OFF_BAR + 8192

__device__ __forceinline__ unsigned short f2bf(float f) {
  unsigned u = __float_as_uint(f);
  u += 0x7FFFu + ((u >> 16) & 1u);   // round-nearest-even
  return (unsigned short)(u >> 16);
}
__device__ __forceinline__ float sigm_(float x) { return 1.0f / (1.0f + __expf(-x)); }
__device__ __forceinline__ float tanh_(float x) {
  float t = __expf(-2.0f * fabsf(x));
  float r = (1.0f - t) / (1.0f + t);
  return x < 0.0f ? -r : r;
}
__device__ __forceinline__ f32x4 mfma16(bf16x8 a, bf16x8 b, f32x4 c) {
  return __builtin_amdgcn_mfma_f32_16x16x32_bf16(a, b, c, 0, 0, 0);
}

// 64-block group barrier (group = m). Leaves keyed by bid&7: exactly 8
// arrivals/leaf/phase regardless of physical XCD placement. Monotonic
// counters (zeroed once per launch). phase is 1-based.
__device__ __forceinline__ void group_barrier(unsigned* bar, unsigned phase, int m, int leafid) {
  __syncthreads();
  if (threadIdx.x == 0) {
    __builtin_amdgcn_fence(__ATOMIC_RELEASE, "agent");
    unsigned* leaf = bar + (m * 16 + leafid) * 32;
    unsigned* root = bar + (m * 16 + 8) * 32;
    unsigned old = __hip_atomic_fetch_add(leaf, 1u, __ATOMIC_RELAXED, __HIP_MEMORY_SCOPE_AGENT);
    if (old + 1u == phase * 8u) {   // last of this leaf's 8 arrivals this phase
      __hip_atomic_fetch_add(root, 1u, __ATOMIC_RELAXED, __HIP_MEMORY_SCOPE_AGENT);
    }
    unsigned rt = phase * 8u;
    int spins = 0;
    while (__hip_atomic_load(root, __ATOMIC_RELAXED, __HIP_MEMORY_SCOPE_AGENT) < rt) {
      if (++spins > (1 << 22)) break;   // bail -> wrong answer instead of hang
    }
    __builtin_amdgcn_fence(__ATOMIC_ACQUIRE, "agent");
  }
  __syncthreads();
}

// ---------------- prep kernels ----------------
__global__ void k_zero(unsigned* __restrict__ p, long n) {
  long i = (long)blockIdx.x * blockDim.x + threadIdx.x;
  long s = (long)gridDim.x * blockDim.x;
  for (; i < n; i += s) p[i] = 0u;
}

// pack W as B[col][k], col = bh*64 + gate*16 + h  -> wrow = gate*HID + bh*16 + h
__global__ void k_packw(const float* __restrict__ Wih, const float* __restrict__ Whh,
                        unsigned short* __restrict__ out, int kih, int K) {
  int i = blockIdx.x * blockDim.x + threadIdx.x;
  int n = 4096 * K;
  int stride = gridDim.x * blockDim.x;
  for (; i < n; i += stride) {
    int p = i / K, k = i - p * K;
    int bh = p >> 6, g = (p >> 4) & 3, h = p & 15;
    int wrow = g * HID + bh * 16 + h;
    float v = (k < kih) ? Wih[(size_t)wrow * kih + k] : Whh[(size_t)wrow * HID + (k - kih)];
    out[i] = f2bf(v);
  }
}

__global__ void k_convx(const float* __restrict__ x, unsigned short* __restrict__ xb) {
  int i = blockIdx.x * blockDim.x + threadIdx.x;
  int stride = gridDim.x * blockDim.x;
  for (; i < TT * BAT * INP; i += stride) xb[i] = f2bf(x[i]);
}

__global__ void k_bias(const float* __restrict__ bih1, const float* __restrict__ bhh1,
                       const float* __restrict__ bih2, const float* __restrict__ bhh2,
                       float* __restrict__ b1p, float* __restrict__ b2p) {
  int p = blockIdx.x * blockDim.x + threadIdx.x;
  if (p < 4096) {
    int bh = p >> 6, g = (p >> 4) & 3, h = p & 15;
    int wrow = g * HID + bh * 16 + h;
    b1p[p] = bih1[wrow] + bhh1[wrow];
    b2p[p] = bih2[wrow] + bhh2[wrow];
  }
}

// ---------------- main persistent kernel ----------------
// block(bid): m = bid>>6 (64-row batch tile), bh = bid&63 (16-h tile).
// Each wave computes the full 64x64 gate tile over a K/4 slice; partials
// summed through LDS. Fragment maps (m89-verified):
//   A frag: lane -> row l15, k = kq*8.. ; B frag same map on packed [col][k];
//   C/D:    col = lane&15, row = (lane>>4)*4 + reg.
__global__ __launch_bounds__(NTHR, 1) void k_lstm(
    const unsigned short* __restrict__ BA, const unsigned short* __restrict__ BB,
    const unsigned short* __restrict__ XB,
    unsigned short* __restrict__ H1, unsigned short* __restrict__ H2,
    float* __restrict__ C1, float* __restrict__ C2,
    const float* __restrict__ B1P, const float* __restrict__ B2P,
    const float* __restrict__ W2, float* __restrict__ YACC,
    unsigned* __restrict__ BAR)
{
  __shared__ float LDSF[4][64][64];   // 65536 B: per-wave partial 64x64 (XOR-swizzled cols)

  const int bid = blockIdx.x;
  const int m = bid >> 6, bh = bid & 63;
  const int leafid = bid & 7;
  const int tid = threadIdx.x;
  const int lane = tid & 63, wave = tid >> 6;
  const int l15 = lane & 15, kq = lane >> 4;
  const int rowb = m * 64;

  // reduce/epilogue mapping: thread owns h = hh (1 col), rows rg*4..+3, all 4 gates
  const int hh = tid & 15, rg = tid >> 4;           // rg 0..15
  const int swz = (rg & 3) << 4;                     // kq-of-row XOR key
  const int hcol = bh * 16 + hh;                     // global h index
  const float w2v = W2[hcol];
  const int colb = bh * 64;
  const float ba0 = B1P[colb + hh], ba1 = B1P[colb + 16 + hh],
              ba2 = B1P[colb + 32 + hh], ba3 = B1P[colb + 48 + hh];
  const float bb0 = B2P[colb + hh], bb1 = B2P[colb + 16 + hh],
              bb2 = B2P[colb + 32 + hh], bb3 = B2P[colb + 48 + hh];

  // B-fragment pointers (per gate), packed [col][k], col = bh*64 + g*16 + l15
  const bf16x8* fb[4]; const bf16x8* gb[4];
#pragma unroll
  for (int g = 0; g < 4; ++g) {
    fb[g] = (const bf16x8*)(BA + (size_t)(colb + g * 16 + l15) * KA);
    gb[g] = (const bf16x8*)(BB + (size_t)(colb + g * 16 + l15) * KB);
  }

  // GEMM1 K-chunk split (34 chunks of 32): waves get 9,9,8,8
  const int c0a = wave * 8 + (wave < 2 ? wave : 2);
  const int c1a = c0a + (wave < 2 ? 9 : 8);

  for (int p = 0; p <= TT; ++p) {
    const int cur = p & 1, prv = cur ^ 1;

    // ======== layer 1, step p ========
    if (p < TT) {
      f32x4 acc[4][4];
#pragma unroll
      for (int i = 0; i < 4; ++i)
#pragma unroll
        for (int g = 0; g < 4; ++g) acc[i][g] = (f32x4){0.f, 0.f, 0.f, 0.f};

      const bf16x8* xbp = (const bf16x8*)XB + (size_t)p * BAT * 8;     // + row*8
      const bf16x8* h1p = (const bf16x8*)(H1 + (size_t)prv * SZH);     // + row*128
      for (int c = c0a; c < c1a; ++c) {
        bf16x8 bfr[4];
#pragma unroll
        for (int g = 0; g < 4; ++g) bfr[g] = fb[g][c * 4 + kq];
        bf16x8 afr[4];
        if (c < 2) {          // x part: k = c*32, row stride 64 elems = 8 frags
#pragma unroll
          for (int i = 0; i < 4; ++i)
            afr[i] = xbp[(rowb + i * 16 + l15) * 8 + c * 4 + kq];
        } else {              // h1 part: k-64 -> chunk c-2, row stride 128 frags
#pragma unroll
          for (int i = 0; i < 4; ++i)
            afr[i] = h1p[(rowb + i * 16 + l15) * 128 + (c - 2) * 4 + kq];
        }
#pragma unroll
        for (int i = 0; i < 4; ++i)
#pragma unroll
          for (int g = 0; g < 4; ++g) acc[i][g] = mfma16(afr[i], bfr[g], acc[i][g]);
      }
      // partials -> LDS (row = i*16+kq*4+j, col = (g*16+l15) ^ (kq<<4))
#pragma unroll
      for (int i = 0; i < 4; ++i)
#pragma unroll
        for (int g = 0; g < 4; ++g) {
          int colS = (g * 16 + l15) ^ (kq << 4);
#pragma unroll
          for (int j = 0; j < 4; ++j) LDSF[wave][i * 16 + kq * 4 + j][colS] = acc[i][g][j];
        }
      __syncthreads();

      // reduce + LSTM cell 1
      {
        unsigned short* h1w = H1 + (size_t)cur * SZH;
#pragma unroll
        for (int u = 0; u < 4; ++u) {
          int r = rg * 4 + u;
          int c0 = (0 * 16 + hh) ^ swz, c1 = (1 * 16 + hh) ^ swz,
              c2 = (2 * 16 + hh) ^ swz, c3 = (3 * 16 + hh) ^ swz;
          float gi = LDSF[0][r][c0] + LDSF[1][r][c0] + LDSF[2][r][c0] + LDSF[3][r][c0] + ba0;
          float gf = LDSF[0][r][c1] + LDSF[1][r][c1] + LDSF[2][r][c1] + LDSF[3][r][c1] + ba1;
          float gg = LDSF[0][r][c2] + LDSF[1][r][c2] + LDSF[2][r][c2] + LDSF[3][r][c2] + ba2;
          float go = LDSF[0][r][c3] + LDSF[1][r][c3] + LDSF[2][r][c3] + LDSF[3][r][c3] + ba3;
          size_t ci = (size_t)(rowb + r) * HID + hcol;
          float cn = sigm_(gf) * C1[ci] + sigm_(gi) * tanh_(gg);
          float hn = sigm_(go) * tanh_(cn);
          C1[ci] = cn;
          h1w[ci] = f2bf(hn);
        }
      }
      __syncthreads();   // protect LDSF reuse by layer 2
    }

    // ======== layer 2, step p-1 ========
    if (p >= 1) {
      f32x4 acc[4][4];
#pragma unroll
      for (int i = 0; i < 4; ++i)
#pragma unroll
        for (int g = 0; g < 4; ++g) acc[i][g] = (f32x4){0.f, 0.f, 0.f, 0.f};

      // A: k<1024 from h1(p-1)=H1[prv], else h2(p-2)=H2[cur]; 64 chunks, 16/wave
      const bf16x8* a2p = (wave < 2) ? (const bf16x8*)(H1 + (size_t)prv * SZH)
                                     : (const bf16x8*)(H2 + (size_t)cur * SZH);
      const int fofs = (wave < 2) ? 0 : 128;   // subtract 1024 elems = 128 frags
      const int cB0 = wave * 16, cB1 = cB0 + 16;
      for (int c = cB0; c < cB1; ++c) {
        bf16x8 bfr[4];
#pragma unroll
        for (int g = 0; g < 4; ++g) bfr[g] = gb[g][c * 4 + kq];
        bf16x8 afr[4];
#pragma unroll
        for (int i = 0; i < 4; ++i)
          afr[i] = a2p[(rowb + i * 16 + l15) * 128 + c * 4 + kq - fofs];
#pragma unroll
        for (int i = 0; i < 4; ++i)
#pragma unroll
          for (int g = 0; g < 4; ++g) acc[i][g] = mfma16(afr[i], bfr[g], acc[i][g]);
      }
#pragma unroll
      for (int i = 0; i < 4; ++i)
#pragma unroll
        for (int g = 0; g < 4; ++g) {
          int colS = (g * 16 + l15) ^ (kq << 4);
#pragma unroll
          for (int j = 0; j < 4; ++j) LDSF[wave][i * 16 + kq * 4 + j][colS] = acc[i][g][j];
        }
      __syncthreads();

      // reduce + LSTM cell 2 + y partial
      {
        unsigned short* h2w = H2 + (size_t)prv * SZH;   // h2(p-1) -> buffer (p-1)&1
#pragma unroll
        for (int u = 0; u < 4; ++u) {
          int r = rg * 4 + u;
          int c0 = (0 * 16 + hh) ^ swz, c1 = (1 * 16 + hh) ^ swz,
              c2 = (2 * 16 + hh) ^ swz, c3 = (3 * 16 + hh) ^ swz;
          float gi = LDSF[0][r][c0] + LDSF[1][r][c0] + LDSF[2][r][c0] + LDSF[3][r][c0] + bb0;
          float gf = LDSF[0][r][c1] + LDSF[1][r][c1] + LDSF[2][r][c1] + LDSF[3][r][c1] + bb1;
          float gg = LDSF[0][r][c2] + LDSF[1][r][c2] + LDSF[2][r][c2] + LDSF[3][r][c2] + bb2;
          float go = LDSF[0][r][c3] + LDSF[1][r][c3] + LDSF[2][r][c3] + LDSF[3][r][c3] + bb3;
          size_t ci = (size_t)(rowb + r) * HID + hcol;
          float cn = sigm_(gf) * C2[ci] + sigm_(gi) * tanh_(gg);
          float hn = sigm_(go) * tanh_(cn);
          C2[ci] = cn;
          h2w[ci] = f2bf(hn);
          // y[t=p-1][rowb+r] partial over this thread-group's 16 h values
          float v = hn * w2v;
          v += __shfl_xor(v, 1);
          v += __shfl_xor(v, 2);
          v += __shfl_xor(v, 4);
          v += __shfl_xor(v, 8);
          if (hh == 0) atomicAdd(YACC + (p - 1) * BAT + rowb + r, v);
        }
      }
    }

    if (p < TT) group_barrier(BAR, (unsigned)(p + 1), m, leafid);
  }
}

__global__ void k_fin(const float* __restrict__ yacc, const float* __restrict__ b2,
                      float* __restrict__ out) {
  int i = blockIdx.x * blockDim.x + threadIdx.x;
  if (i < TT * BAT) out[i] = 1.0f / (1.0f + __expf(-(yacc[i] + b2[0])));
}

// ---------------------------------------------------------------------------
extern "C" void kernel_launch(void* const* d_in, const int* in_sizes, int n_in,
                              void* d_out, int out_size, void* d_ws, size_t ws_size,
                              hipStream_t stream) {
  const float* x    = (const float*)d_in[0];
  const float* Wih1 = (const float*)d_in[1];
  const float* Whh1 = (const float*)d_in[2];
  const float* bih1 = (const float*)d_in[3];
  const float* bhh1 = (const float*)d_in[4];
  const float* Wih2 = (const float*)d_in[5];
  const float* Whh2 = (const float*)d_in[6];
  const float* bih2 = (const float*)d_in[7];
  const float* bhh2 = (const float*)d_in[8];
  const float* W2   = (const float*)d_in[9];
  const float* b2   = (const float*)d_in[10];
  (void)in_sizes; (void)n_in; (void)out_size; (void)ws_size;

  char* ws = (char*)d_ws;
  unsigned short* BA  = (unsigned short*)(ws + OFF_BA);
  unsigned short* BBp = (unsigned short*)(ws + OFF_BB);
  unsigned short* XBp = (unsigned short*)(ws + OFF_XB);
  unsigned short* H1  = (unsigned short*)(ws + OFF_H1);
  unsigned short* H2  = (unsigned short*)(ws + OFF_H2);
  float* C1   = (float*)(ws + OFF_C1);
  float* C2   = (float*)(ws + OFF_C2);
  float* YACC = (float*)(ws + OFF_Y);
  float* B1P  = (float*)(ws + OFF_B1P);
  float* B2P  = (float*)(ws + OFF_B2P);
  unsigned* BAR = (unsigned*)(ws + OFF_BAR);

  // zero h/c state, y accumulator, bias area, barrier counters (contiguous)
  k_zero<<<512, 256, 0, stream>>>((unsigned*)(ws + OFF_H1), (long)((WS_END - OFF_H1) / 4));
  k_packw<<<1024, 256, 0, stream>>>(Wih1, Whh1, BA, INP, KA);
  k_packw<<<2048, 256, 0, stream>>>(Wih2, Whh2, BBp, HID, KB);
  k_convx<<<1024, 256, 0, stream>>>(x, XBp);
  k_bias<<<16, 256, 0, stream>>>(bih1, bhh1, bih2, bhh2, B1P, B2P);
  k_lstm<<<NBLK, NTHR, 0, stream>>>(BA, BBp, XBp, H1, H2, C1, C2, B1P, B2P, W2, YACC, BAR);
  k_fin<<<512, 256, 0, stream>>>(YACC, b2, (float*)d_out);
}

// Round 7
// 15228.349 us; speedup vs baseline: 1.4331x; 1.4331x over previous
//
#include <hip/hip_runtime.h>
#include <stdint.h>

// ---------------------------------------------------------------------------
// 2-layer LSTM (T=512, B=256, IN=64, H=1024) + Linear(H->1) + sigmoid.
// Persistent kernel, 256 blocks (1/CU), layers pipelined: phase p =
// layer1(p) + layer2(p-1), ONE group barrier per phase.
// Evidence (round 3): FETCH 18MB/phase = weights refetched past L2 after
// every acquire-fence invalidate; 512 GB/s latency-limited => 21.8ms.
// Design:
//  * W2 panel (262KB) -> VGPRs (K-split over 4 waves, 256 VGPR/lane, static
//    indexing). W1 panel (139KB) -> static LDS. C1/C2 -> registers.
//    Fences cannot evict regs/LDS; per-phase global traffic = H/x/Y only.
//  * GEMM1 row-split (no reduce); GEMM2 K-split + balanced 3-round LDS
//    all-to-all (all waves store+load each round, 5 syncthreads).
//  * Epilogue1 before GEMM2: ends acc1 live range early (VGPR hedge),
//    overlaps h1 stores with GEMM2 loads.
//  * m-group = XCD pair (m=(bid&7)>>1): H traffic stays in 2 L2s.
//  * Y atomics: 8 slots per row (8-way contention instead of 64).
//  * Barrier spin bail = 1<<17 (~7ms worst case) so a pathological stall
//    can never look like a dead container to the harness.
// ---------------------------------------------------------------------------

#define TT   512
#define BAT  256
#define INP  64
#define HID  1024
#define KA   1088
#define KB   2048
#define SZH  (BAT*HID)
#define NBLK 256
#define NTHR 256

typedef __attribute__((ext_vector_type(8))) short bf16x8;
typedef __attribute__((ext_vector_type(4))) float f32x4;

// workspace byte offsets (256-aligned)
#define OFF_BA   0ull          // bf16 [4096][1088] packed W layer1
#define OFF_BB   8912896ull    // bf16 [4096][2048] packed W layer2
#define OFF_XB   25690112ull   // bf16 x [512][256][64]
#define OFF_H1   42467328ull   // bf16 h1 [2][256][1024]
#define OFF_H2   43515904ull   // bf16 h2 [2][256][1024]
#define OFF_Y    44564480ull   // f32 yacc [512][256][8]
#define OFF_B1P  48758784ull   // f32 packed bias layer1 [4096]
#define OFF_B2P  48775168ull   // f32 packed bias layer2 [4096]
#define OFF_BAR  48791552ull   // u32 barriers: 4 groups x 16 lines x 128B
#define WS_END   48799744ull

__device__ __forceinline__ unsigned short f2bf(float f) {
  unsigned u = __float_as_uint(f);
  u += 0x7FFFu + ((u >> 16) & 1u);
  return (unsigned short)(u >> 16);
}
__device__ __forceinline__ float sigm_(float x) { return 1.0f / (1.0f + __expf(-x)); }
__device__ __forceinline__ float tanh_(float x) {
  float t = __expf(-2.0f * fabsf(x));
  float r = (1.0f - t) / (1.0f + t);
  return x < 0.0f ? -r : r;
}
__device__ __forceinline__ f32x4 mfma16(bf16x8 a, bf16x8 b, f32x4 c) {
  return __builtin_amdgcn_mfma_f32_16x16x32_bf16(a, b, c, 0, 0, 0);
}

// 64-block group barrier. 8 leaves (8 arrivals each) + root. Monotonic
// counters zeroed once per launch; phase is 1-based.
__device__ __forceinline__ void group_barrier(unsigned* bar, unsigned phase, int m, int leaf) {
  __syncthreads();
  if (threadIdx.x == 0) {
    __builtin_amdgcn_fence(__ATOMIC_RELEASE, "agent");
    unsigned* lp = bar + (m * 16 + leaf) * 32;
    unsigned* rp = bar + (m * 16 + 8) * 32;
    unsigned old = __hip_atomic_fetch_add(lp, 1u, __ATOMIC_RELAXED, __HIP_MEMORY_SCOPE_AGENT);
    if (old + 1u == phase * 8u)
      __hip_atomic_fetch_add(rp, 1u, __ATOMIC_RELAXED, __HIP_MEMORY_SCOPE_AGENT);
    unsigned tgt = phase * 8u;
    int spins = 0;
    while (__hip_atomic_load(rp, __ATOMIC_RELAXED, __HIP_MEMORY_SCOPE_AGENT) < tgt) {
      __builtin_amdgcn_s_sleep(2);
      if (++spins > (1 << 17)) break;   // ~7ms worst case; bail -> wrong answer, never hang
    }
    __builtin_amdgcn_fence(__ATOMIC_ACQUIRE, "agent");
  }
  __syncthreads();
}

// ---------------- prep kernels ----------------
__global__ void k_zero(unsigned* __restrict__ p, long n) {
  long i = (long)blockIdx.x * blockDim.x + threadIdx.x;
  long s = (long)gridDim.x * blockDim.x;
  for (; i < n; i += s) p[i] = 0u;
}

// pack W as B[col][k], col = bh*64 + gate*16 + h  -> wrow = gate*HID + bh*16 + h
__global__ void k_packw(const float* __restrict__ Wih, const float* __restrict__ Whh,
                        unsigned short* __restrict__ out, int kih, int K) {
  int i = blockIdx.x * blockDim.x + threadIdx.x;
  int n = 4096 * K;
  int stride = gridDim.x * blockDim.x;
  for (; i < n; i += stride) {
    int p = i / K, k = i - p * K;
    int bh = p >> 6, g = (p >> 4) & 3, h = p & 15;
    int wrow = g * HID + bh * 16 + h;
    float v = (k < kih) ? Wih[(size_t)wrow * kih + k] : Whh[(size_t)wrow * HID + (k - kih)];
    out[i] = f2bf(v);
  }
}

__global__ void k_convx(const float* __restrict__ x, unsigned short* __restrict__ xb) {
  int i = blockIdx.x * blockDim.x + threadIdx.x;
  int stride = gridDim.x * blockDim.x;
  for (; i < TT * BAT * INP; i += stride) xb[i] = f2bf(x[i]);
}

__global__ void k_bias(const float* __restrict__ bih1, const float* __restrict__ bhh1,
                       const float* __restrict__ bih2, const float* __restrict__ bhh2,
                       float* __restrict__ b1p, float* __restrict__ b2p) {
  int p = blockIdx.x * blockDim.x + threadIdx.x;
  if (p < 4096) {
    int bh = p >> 6, g = (p >> 4) & 3, h = p & 15;
    int wrow = g * HID + bh * 16 + h;
    b1p[p] = bih1[wrow] + bhh1[wrow];
    b2p[p] = bih2[wrow] + bhh2[wrow];
  }
}

// ---------------- main persistent kernel ----------------
// bid -> m = (bid&7)>>1 (64-row tile, pinned to XCD pair), bh = (bid>>3)|((bid&1)<<5).
// GEMM1: row-split (wave w: rows 16w..+15, full K, W1 B-frags from LDS).
// GEMM2: K-split (wave w: K-chunks 16w..+15, W2 B-frags in VGPRs), then
//        balanced 3-round LDS all-to-all; wave w ends owning rows 16w..+15.
__global__ __launch_bounds__(NTHR, 1) void k_lstm(
    const unsigned short* __restrict__ BA, const unsigned short* __restrict__ BB,
    const unsigned short* __restrict__ XB,
    unsigned short* __restrict__ H1, unsigned short* __restrict__ H2,
    const float* __restrict__ B1P, const float* __restrict__ B2P,
    const float* __restrict__ W2, float* __restrict__ YACC,
    unsigned* __restrict__ BAR)
{
  __shared__ bf16x8 W1L[34 * 4 * 4 * 16];   // 139264 B: W1 panel frags [c][kq][g][l15]
  __shared__ f32x4  BUF[4 * 4 * 4 * 16];    //  16384 B: all-to-all [slot][g][kq][l15]

  const int bid = blockIdx.x;
  const int s = bid & 1;
  const int m = (bid & 7) >> 1;
  const int bh = (bid >> 3) | (s << 5);
  const int leaf = s * 4 + ((bid >> 3) & 3);
  const int tid = threadIdx.x;
  const int lane = tid & 63, wave = tid >> 6;
  const int l15 = lane & 15, kq = lane >> 4;
  const int grow0 = m * 64 + wave * 16;           // this wave's first row
  const int arow = grow0 + l15;                   // A-fragment row
  const int hcol = bh * 16 + l15;                 // h index this lane owns
  const int colb = bh * 64;

  // ---- one-time init ----
  // W1 -> LDS (frag order: [(c*4+kq)*4+g][l15])
  {
    const int kq2 = tid >> 6, g2 = (tid >> 4) & 3, l2 = tid & 15;
    for (int c = 0; c < 34; ++c) {
      const bf16x8* src = (const bf16x8*)(BA + (size_t)(colb + g2 * 16 + l2) * KA);
      W1L[((c * 4 + kq2) * 4 + g2) * 16 + l2] = src[c * 4 + kq2];
    }
  }
  // W2 K-slice -> VGPRs (static indexing everywhere)
  bf16x8 w2r[16][4];
#pragma unroll
  for (int g = 0; g < 4; ++g) {
    const bf16x8* src = (const bf16x8*)(BB + (size_t)(colb + g * 16 + l15) * KB);
#pragma unroll
    for (int cc = 0; cc < 16; ++cc) w2r[cc][g] = src[(wave * 16 + cc) * 4 + kq];
  }
  const float ba0 = B1P[colb + l15], ba1 = B1P[colb + 16 + l15],
              ba2 = B1P[colb + 32 + l15], ba3 = B1P[colb + 48 + l15];
  const float bb0 = B2P[colb + l15], bb1 = B2P[colb + 16 + l15],
              bb2 = B2P[colb + 32 + l15], bb3 = B2P[colb + 48 + l15];
  const float w2v = W2[hcol];
  float c1r[4] = {0.f, 0.f, 0.f, 0.f};
  float c2r[4] = {0.f, 0.f, 0.f, 0.f};
  __syncthreads();

  for (int p = 0; p <= TT; ++p) {
    const int cur = p & 1, prv = cur ^ 1;

    // ======== GEMM1 + epilogue1: layer 1 step p (rows grow0..+15) ========
    if (p < TT) {
      f32x4 acc1[4];
#pragma unroll
      for (int g = 0; g < 4; ++g) acc1[g] = (f32x4){0.f, 0.f, 0.f, 0.f};
      const bf16x8* xf  = (const bf16x8*)XB + ((size_t)p * BAT + arow) * 8;
      const bf16x8* h1f = (const bf16x8*)(H1 + (size_t)prv * SZH) + (size_t)arow * 128;
#pragma unroll
      for (int c = 0; c < 34; ++c) {
        bf16x8 a = (c < 2) ? xf[c * 4 + kq] : h1f[(c - 2) * 4 + kq];
#pragma unroll
        for (int g = 0; g < 4; ++g)
          acc1[g] = mfma16(a, W1L[((c * 4 + kq) * 4 + g) * 16 + l15], acc1[g]);
      }
      // epilogue 1 immediately (acc1 dies before acc2 allocates).
      // Writes H1[cur]; GEMM2 reads only H1[prv]/H2[cur] -> no conflict.
      unsigned short* h1w = H1 + (size_t)cur * SZH;
#pragma unroll
      for (int j = 0; j < 4; ++j) {
        float gi = acc1[0][j] + ba0, gf = acc1[1][j] + ba1,
              gg = acc1[2][j] + ba2, go = acc1[3][j] + ba3;
        float cn = sigm_(gf) * c1r[j] + sigm_(gi) * tanh_(gg);
        float hn = sigm_(go) * tanh_(cn);
        c1r[j] = cn;
        h1w[(size_t)(grow0 + kq * 4 + j) * HID + hcol] = f2bf(hn);
      }
    }

    // ======== GEMM2: gates2(p-1) = [h1(p-1) | h2(p-2)] @ W2 (K-split) ========
    if (p >= 1) {
      f32x4 acc2[4][4];   // [row-tile][gate]
#pragma unroll
      for (int i = 0; i < 4; ++i)
#pragma unroll
        for (int g = 0; g < 4; ++g) acc2[i][g] = (f32x4){0.f, 0.f, 0.f, 0.f};
      const bf16x8* af = (wave < 2) ? (const bf16x8*)(H1 + (size_t)prv * SZH)
                                    : (const bf16x8*)(H2 + (size_t)cur * SZH);
      const int fo = (wave < 2) ? wave * 64 : (wave - 2) * 64;   // frag offset of chunk base
#pragma unroll
      for (int cc = 0; cc < 16; ++cc) {
        bf16x8 afr[4];
#pragma unroll
        for (int i = 0; i < 4; ++i)
          afr[i] = af[(size_t)(m * 64 + i * 16 + l15) * 128 + fo + cc * 4 + kq];
#pragma unroll
        for (int i = 0; i < 4; ++i)
#pragma unroll
          for (int g = 0; g < 4; ++g) acc2[i][g] = mfma16(afr[i], w2r[cc][g], acc2[i][g]);
      }

      // balanced all-to-all: round d, wave w publishes its partial of tile
      // (w+d)&3 into slot w, accumulates tile w from slot (w-d)&3. acc2
      // register indices stay compile-time via the t-branches (rule #20).
#pragma unroll
      for (int d = 1; d < 4; ++d) {
#pragma unroll
        for (int t = 0; t < 4; ++t) {
          if (((wave + d) & 3) == t) {
#pragma unroll
            for (int g = 0; g < 4; ++g)
              BUF[((wave * 4 + g) * 4 + kq) * 16 + l15] = acc2[t][g];
          }
        }
        __syncthreads();
#pragma unroll
        for (int t = 0; t < 4; ++t) {
          if (wave == t) {
            const int rs = (t - d) & 3;
#pragma unroll
            for (int g = 0; g < 4; ++g)
              acc2[t][g] += BUF[((rs * 4 + g) * 4 + kq) * 16 + l15];
          }
        }
        if (d < 3) __syncthreads();   // protect BUF overwrite next round
      }

      // epilogue 2 on wave-owned rows (extract with static indices)
      unsigned short* h2w = H2 + (size_t)prv * SZH;   // h2(p-1) -> buffer (p-1)&1
      f32x4 g0, g1, g2, g3;
#pragma unroll
      for (int t = 0; t < 4; ++t)
        if (wave == t) { g0 = acc2[t][0]; g1 = acc2[t][1]; g2 = acc2[t][2]; g3 = acc2[t][3]; }
#pragma unroll
      for (int j = 0; j < 4; ++j) {
        float gi = g0[j] + bb0, gf = g1[j] + bb1, gg = g2[j] + bb2, go = g3[j] + bb3;
        float cn = sigm_(gf) * c2r[j] + sigm_(gi) * tanh_(gg);
        float hn = sigm_(go) * tanh_(cn);
        c2r[j] = cn;
        int gr = grow0 + kq * 4 + j;
        h2w[(size_t)gr * HID + hcol] = f2bf(hn);
        float v = hn * w2v;
        v += __shfl_xor(v, 1);
        v += __shfl_xor(v, 2);
        v += __shfl_xor(v, 4);
        v += __shfl_xor(v, 8);
        if (l15 == 0) atomicAdd(YACC + ((size_t)(p - 1) * BAT + gr) * 8 + ((bid >> 3) & 7), v);
      }
    }

    if (p < TT) group_barrier(BAR, (unsigned)(p + 1), m, leaf);
  }
}

__global__ void k_fin(const float* __restrict__ yacc, const float* __restrict__ b2,
                      float* __restrict__ out) {
  int i = blockIdx.x * blockDim.x + threadIdx.x;
  if (i < TT * BAT) {
    const float* y = yacc + (size_t)i * 8;
    float a = (y[0] + y[1]) + (y[2] + y[3]) + ((y[4] + y[5]) + (y[6] + y[7]));
    out[i] = 1.0f / (1.0f + __expf(-(a + b2[0])));
  }
}

// ---------------------------------------------------------------------------
extern "C" void kernel_launch(void* const* d_in, const int* in_sizes, int n_in,
                              void* d_out, int out_size, void* d_ws, size_t ws_size,
                              hipStream_t stream) {
  const float* x    = (const float*)d_in[0];
  const float* Wih1 = (const float*)d_in[1];
  const float* Whh1 = (const float*)d_in[2];
  const float* bih1 = (const float*)d_in[3];
  const float* bhh1 = (const float*)d_in[4];
  const float* Wih2 = (const float*)d_in[5];
  const float* Whh2 = (const float*)d_in[6];
  const float* bih2 = (const float*)d_in[7];
  const float* bhh2 = (const float*)d_in[8];
  const float* W2   = (const float*)d_in[9];
  const float* b2   = (const float*)d_in[10];
  (void)in_sizes; (void)n_in; (void)out_size; (void)ws_size;

  char* ws = (char*)d_ws;
  unsigned short* BA  = (unsigned short*)(ws + OFF_BA);
  unsigned short* BBp = (unsigned short*)(ws + OFF_BB);
  unsigned short* XBp = (unsigned short*)(ws + OFF_XB);
  unsigned short* H1  = (unsigned short*)(ws + OFF_H1);
  unsigned short* H2  = (unsigned short*)(ws + OFF_H2);
  float* YACC = (float*)(ws + OFF_Y);
  float* B1P  = (float*)(ws + OFF_B1P);
  float* B2P  = (float*)(ws + OFF_B2P);
  unsigned* BAR = (unsigned*)(ws + OFF_BAR);

  k_zero<<<512, 256, 0, stream>>>((unsigned*)(ws + OFF_H1), (long)((WS_END - OFF_H1) / 4));
  k_packw<<<1024, 256, 0, stream>>>(Wih1, Whh1, BA, INP, KA);
  k_packw<<<2048, 256, 0, stream>>>(Wih2, Whh2, BBp, HID, KB);
  k_convx<<<1024, 256, 0, stream>>>(x, XBp);
  k_bias<<<16, 256, 0, stream>>>(bih1, bhh1, bih2, bhh2, B1P, B2P);
  k_lstm<<<NBLK, NTHR, 0, stream>>>(BA, BBp, XBp, H1, H2, B1P, B2P, W2, YACC, BAR);
  k_fin<<<512, 256, 0, stream>>>(YACC, b2, (float*)d_out);
}